// Round 3
// baseline (1047.478 us; speedup 1.0000x reference)
//
#include <hip/hip_runtime.h>

#define NS 3200
#define NQ 200000
#define NTOT (NS + NQ)      // 203200 = 64 * 3175
#define KIN 512
#define ED 128
#define NC 64
#define INV_N (1.0f / (float)NTOT)
#define PGRID 512           // propagate grid; partial slabs sized to this

typedef short short8 __attribute__((ext_vector_type(8)));
typedef short short4v __attribute__((ext_vector_type(4)));
typedef float floatx4 __attribute__((ext_vector_type(4)));

static __device__ __forceinline__ unsigned short f2bf(float f) {
    unsigned int u = __float_as_uint(f);
    u += 0x7FFF + ((u >> 16) & 1);          // round-to-nearest-even
    return (unsigned short)(u >> 16);
}
static __device__ __forceinline__ float bf2f(unsigned short h) {
    return __uint_as_float(((unsigned int)h) << 16);
}

// ---------------------------------------------------------------------------
// One-time: WTbf[n][k] = bf16(W[k][n])   (128 x 512)
// ---------------------------------------------------------------------------
__global__ __launch_bounds__(256) void prep_wt(const float* __restrict__ W,
                                               unsigned short* __restrict__ WT)
{
    int idx = blockIdx.x * 256 + threadIdx.x;
#pragma unroll
    for (int p = 0; p < 4; ++p) {
        int id = idx + p * 16384;          // 64 blocks * 256 thr * 4 = 65536
        int n = id >> 9, k = id & 511;
        WT[n * 512 + k] = f2bf(W[k * 128 + n]);
    }
}

// ---------------------------------------------------------------------------
// Encoder v2: zero-LDS, zero-barrier streaming MFMA.
// BM=256, 512 thr (8 waves), each wave owns 32 rows x 128 cols.
// A-frags: float4 pairs straight from X (L1 catches the 64B-line reuse across
// quads; HBM traffic = exactly one pass over X). B-frags: direct from WT,
// which is 128 KB and L1/L2-resident. K loop fully unrolled, no syncs ->
// compiler pipelines loads across MFMAs freely.
// ---------------------------------------------------------------------------
__global__ __launch_bounds__(512) void encode_mfma(
    const float* __restrict__ X, const unsigned short* __restrict__ WT,
    const float* __restrict__ bias, unsigned short* __restrict__ emb,
    float* __restrict__ en2, int nrows)
{
    const int t = threadIdx.x;
    const int w = t >> 6, lane = t & 63, q = lane >> 4, i = lane & 15;
    const long row0 = (long)blockIdx.x * 256;

    // A-operand row per lane (two 16-row fragments), clamped for the tail block
    long xr0 = row0 + w * 32 + i;
    long xr1 = xr0 + 16;
    if (xr0 > nrows - 1) xr0 = nrows - 1;
    if (xr1 > nrows - 1) xr1 = nrows - 1;
    const float* xp0 = &X[xr0 * KIN + q * 8];
    const float* xp1 = &X[xr1 * KIN + q * 8];
    const unsigned short* wp = &WT[(long)i * 512 + q * 8];

    floatx4 acc0[8], acc1[8];
#pragma unroll
    for (int ct = 0; ct < 8; ++ct) {
        acc0[ct] = (floatx4){0.f, 0.f, 0.f, 0.f};
        acc1[ct] = (floatx4){0.f, 0.f, 0.f, 0.f};
    }

#pragma unroll
    for (int kk = 0; kk < KIN; kk += 32) {
        floatx4 f0a = *(const floatx4*)(xp0 + kk);
        floatx4 f0b = *(const floatx4*)(xp0 + kk + 4);
        floatx4 f1a = *(const floatx4*)(xp1 + kk);
        floatx4 f1b = *(const floatx4*)(xp1 + kk + 4);
        short8 a0, a1;
        a0[0] = (short)f2bf(f0a[0]); a0[1] = (short)f2bf(f0a[1]);
        a0[2] = (short)f2bf(f0a[2]); a0[3] = (short)f2bf(f0a[3]);
        a0[4] = (short)f2bf(f0b[0]); a0[5] = (short)f2bf(f0b[1]);
        a0[6] = (short)f2bf(f0b[2]); a0[7] = (short)f2bf(f0b[3]);
        a1[0] = (short)f2bf(f1a[0]); a1[1] = (short)f2bf(f1a[1]);
        a1[2] = (short)f2bf(f1a[2]); a1[3] = (short)f2bf(f1a[3]);
        a1[4] = (short)f2bf(f1b[0]); a1[5] = (short)f2bf(f1b[1]);
        a1[6] = (short)f2bf(f1b[2]); a1[7] = (short)f2bf(f1b[3]);
#pragma unroll
        for (int ct = 0; ct < 8; ++ct) {
            short8 b = *(const short8*)&wp[ct * 16 * 512 + kk];
            acc0[ct] = __builtin_amdgcn_mfma_f32_16x16x32_bf16(a0, b, acc0[ct], 0, 0, 0);
            acc1[ct] = __builtin_amdgcn_mfma_f32_16x16x32_bf16(a1, b, acc1[ct], 0, 0, 0);
        }
    }

    float bb[8];
#pragma unroll
    for (int ct = 0; ct < 8; ++ct) bb[ct] = bias[ct * 16 + i];

#define EPILOGUE(ACC, RF)                                                      \
    {                                                                          \
        _Pragma("unroll")                                                      \
        for (int r = 0; r < 4; ++r) {                                          \
            long row = row0 + w * 32 + (RF) * 16 + q * 4 + r;                  \
            bool ok = row < nrows;                                             \
            float s = 0.f;                                                     \
            _Pragma("unroll")                                                  \
            for (int ct = 0; ct < 8; ++ct) {                                   \
                float v = ACC[ct][r] + bb[ct];                                 \
                if (ok) emb[row * ED + ct * 16 + i] = f2bf(v);                 \
                s += v * v;                                                    \
            }                                                                  \
            s += __shfl_xor(s, 1); s += __shfl_xor(s, 2);                      \
            s += __shfl_xor(s, 4); s += __shfl_xor(s, 8);                      \
            if (ok && i == 0) en2[row] = s;                                    \
        }                                                                      \
    }

    EPILOGUE(acc0, 0)
    EPILOGUE(acc1, 1)
#undef EPILOGUE
}

// ---------------------------------------------------------------------------
// Initial prototypes: per-class mean of support embeddings.
// ---------------------------------------------------------------------------
__global__ __launch_bounds__(128) void proto_init(
    const unsigned short* __restrict__ emb, const int* __restrict__ labels,
    float* __restrict__ proto)
{
    const int c = blockIdx.x, d = threadIdx.x;
    float acc = 0.f; int cnt = 0;
    for (int r4 = 0; r4 < NS; r4 += 4) {
        int4 lb = *(const int4*)&labels[r4];
        if (lb.x == c) { acc += bf2f(emb[(r4 + 0) * ED + d]); cnt++; }
        if (lb.y == c) { acc += bf2f(emb[(r4 + 1) * ED + d]); cnt++; }
        if (lb.z == c) { acc += bf2f(emb[(r4 + 2) * ED + d]); cnt++; }
        if (lb.w == c) { acc += bf2f(emb[(r4 + 3) * ED + d]); cnt++; }
    }
    proto[c * ED + d] = acc / fmaxf((float)cnt, 1.0f);
}

// ---------------------------------------------------------------------------
// Fused propagation: S = E @ P^T (MFMA) -> softmax (regs) -> P' += A^T @ E (MFMA)
// 256 thr (4 waves), 64-row tiles, grid-stride; per-block partial slab instead
// of global atomics (deterministic, no L2 atomic serialization).
// ---------------------------------------------------------------------------
__global__ __launch_bounds__(256) void propagate(
    const unsigned short* __restrict__ emb, const float* __restrict__ en2,
    const float* __restrict__ proto_src, float scale,
    float* __restrict__ partial)
{
    __shared__ unsigned short Pbf[64 * 136];  // [class][d], stride 136
    __shared__ unsigned short ET[128 * 66];   // [d][row],   stride 66 (b16-write spread)
    __shared__ unsigned short ScT[64 * 72];   // [class][row], stride 72
    __shared__ float pn2s[64];

    const int t = threadIdx.x;
    const int w = t >> 6, lane = t & 63, q = lane >> 4, i = lane & 15;

    // prototype prep: scale, bf16, norms
    {
        int c = t >> 2, part = t & 3;
        const float* src = &proto_src[c * 128 + part * 32];
        float sqv = 0.f;
#pragma unroll 8
        for (int j = 0; j < 32; ++j) {
            float v = src[j] * scale;
            Pbf[c * 136 + part * 32 + j] = f2bf(v);
            sqv += v * v;
        }
        sqv += __shfl_xor(sqv, 1);
        sqv += __shfl_xor(sqv, 2);
        if (part == 0) pn2s[c] = sqv;
    }
    __syncthreads();

    // hoist B-fragments (prototypes) + pn to registers — constant over tiles
    short8 bP[4][4];
#pragma unroll
    for (int ct = 0; ct < 4; ++ct)
#pragma unroll
        for (int ks = 0; ks < 4; ++ks)
            bP[ct][ks] = *(const short8*)&Pbf[(ct * 16 + i) * 136 + ks * 32 + q * 8];
    float pn[4];
#pragma unroll
    for (int ct = 0; ct < 4; ++ct) pn[ct] = pn2s[ct * 16 + i];

    floatx4 acc2[8];
#pragma unroll
    for (int nt = 0; nt < 8; ++nt) acc2[nt] = (floatx4){0.f, 0.f, 0.f, 0.f};

    const int ntiles = NTOT / 64;
    for (int tile = blockIdx.x; tile < ntiles; tile += gridDim.x) {
        const long row0 = (long)tile * 64;

        // A-fragments straight from global bf16 emb (16B/lane)
        short8 aE[4];
#pragma unroll
        for (int ks = 0; ks < 4; ++ks)
            aE[ks] = *(const short8*)&emb[(row0 + w * 16 + i) * ED + ks * 32 + q * 8];
        float en[4];
#pragma unroll
        for (int r = 0; r < 4; ++r) en[r] = en2[row0 + w * 16 + q * 4 + r];

        // transpose E tile into LDS for GEMM2 B-operand
#pragma unroll
        for (int ks = 0; ks < 4; ++ks)
#pragma unroll
            for (int j = 0; j < 8; ++j)
                ET[(ks * 32 + q * 8 + j) * 66 + w * 16 + i] = (unsigned short)aE[ks][j];

        // GEMM1: S[16 rows x 64 classes]
        floatx4 s1[4];
#pragma unroll
        for (int ct = 0; ct < 4; ++ct) s1[ct] = (floatx4){0.f, 0.f, 0.f, 0.f};
#pragma unroll
        for (int ks = 0; ks < 4; ++ks)
#pragma unroll
            for (int ct = 0; ct < 4; ++ct)
                s1[ct] = __builtin_amdgcn_mfma_f32_16x16x32_bf16(aE[ks], bP[ct][ks], s1[ct], 0, 0, 0);

        // softmax over 64 classes (4 cts in regs x 16 lanes of quad)
        float attn[4][4];   // [ct][r]
#pragma unroll
        for (int r = 0; r < 4; ++r) {
            float sc[4];
#pragma unroll
            for (int ct = 0; ct < 4; ++ct) {
                float d2 = en[r] + pn[ct] - 2.f * s1[ct][r];
                sc[ct] = -sqrtf(fmaxf(d2, 0.f));
            }
            float mx = fmaxf(fmaxf(sc[0], sc[1]), fmaxf(sc[2], sc[3]));
            mx = fmaxf(mx, __shfl_xor(mx, 1));
            mx = fmaxf(mx, __shfl_xor(mx, 2));
            mx = fmaxf(mx, __shfl_xor(mx, 4));
            mx = fmaxf(mx, __shfl_xor(mx, 8));
            float sm = 0.f;
#pragma unroll
            for (int ct = 0; ct < 4; ++ct) { attn[ct][r] = __expf(sc[ct] - mx); sm += attn[ct][r]; }
            sm += __shfl_xor(sm, 1);
            sm += __shfl_xor(sm, 2);
            sm += __shfl_xor(sm, 4);
            sm += __shfl_xor(sm, 8);
            float inv = 1.f / sm;
#pragma unroll
            for (int ct = 0; ct < 4; ++ct) attn[ct][r] *= inv;
        }
        // write attn transposed: ScT[class][row] (4 rows packed per b64 write)
#pragma unroll
        for (int ct = 0; ct < 4; ++ct) {
            short4v pk;
            pk[0] = (short)f2bf(attn[ct][0]); pk[1] = (short)f2bf(attn[ct][1]);
            pk[2] = (short)f2bf(attn[ct][2]); pk[3] = (short)f2bf(attn[ct][3]);
            *(short4v*)&ScT[(ct * 16 + i) * 72 + w * 16 + q * 4] = pk;
        }
        __syncthreads();

        // GEMM2: wave w -> classes w*16..+15, all 128 dims, K = 64 rows
#pragma unroll
        for (int ks2 = 0; ks2 < 2; ++ks2) {
            short8 a2 = *(const short8*)&ScT[(w * 16 + i) * 72 + ks2 * 32 + q * 8];
#pragma unroll
            for (int nt = 0; nt < 8; ++nt) {
                union { short8 s; unsigned int u[4]; } b2;
                const unsigned short* base = &ET[(nt * 16 + i) * 66 + ks2 * 32 + q * 8];
                b2.u[0] = *(const unsigned int*)&base[0];
                b2.u[1] = *(const unsigned int*)&base[2];
                b2.u[2] = *(const unsigned int*)&base[4];
                b2.u[3] = *(const unsigned int*)&base[6];
                acc2[nt] = __builtin_amdgcn_mfma_f32_16x16x32_bf16(a2, b2.s, acc2[nt], 0, 0, 0);
            }
        }
        __syncthreads();
    }

    // per-block partial slab (replaces 4.2M global atomics)
    float* myp = partial + (size_t)blockIdx.x * (NC * ED);
#pragma unroll
    for (int nt = 0; nt < 8; ++nt)
#pragma unroll
        for (int r = 0; r < 4; ++r)
            myp[(w * 16 + q * 4 + r) * ED + nt * 16 + i] = acc2[nt][r];
}

// ---------------------------------------------------------------------------
// Sum the PGRID partial slabs -> proto sums (64x128)
// ---------------------------------------------------------------------------
__global__ __launch_bounds__(256) void reduce_partials(
    const float* __restrict__ partial, float* __restrict__ proto)
{
    int idx = blockIdx.x * 256 + threadIdx.x;   // grid 32 -> 8192 outputs
    float s = 0.f;
#pragma unroll 8
    for (int b = 0; b < PGRID; ++b) s += partial[(size_t)b * (NC * ED) + idx];
    proto[idx] = s;
}

// ---------------------------------------------------------------------------
// Final logits: out[q][c] = -sqrt(max(||e||^2 + ||p||^2 - 2 e.p, 0))
// ---------------------------------------------------------------------------
__global__ __launch_bounds__(256) void logits_k(
    const unsigned short* __restrict__ emb, const float* __restrict__ en2,
    const float* __restrict__ proto_src, float scale, float* __restrict__ out)
{
    __shared__ unsigned short Pbf[64 * 136];
    __shared__ float pn2s[64];

    const int t = threadIdx.x;
    const int w = t >> 6, lane = t & 63, q = lane >> 4, i = lane & 15;

    {
        int c = t >> 2, part = t & 3;
        const float* src = &proto_src[c * 128 + part * 32];
        float sqv = 0.f;
#pragma unroll 8
        for (int j = 0; j < 32; ++j) {
            float v = src[j] * scale;
            Pbf[c * 136 + part * 32 + j] = f2bf(v);
            sqv += v * v;
        }
        sqv += __shfl_xor(sqv, 1);
        sqv += __shfl_xor(sqv, 2);
        if (part == 0) pn2s[c] = sqv;
    }
    __syncthreads();

    short8 bP[4][4];
#pragma unroll
    for (int ct = 0; ct < 4; ++ct)
#pragma unroll
        for (int ks = 0; ks < 4; ++ks)
            bP[ct][ks] = *(const short8*)&Pbf[(ct * 16 + i) * 136 + ks * 32 + q * 8];
    float pn[4];
#pragma unroll
    for (int ct = 0; ct < 4; ++ct) pn[ct] = pn2s[ct * 16 + i];

    const int ntiles = NQ / 64;
    for (int tile = blockIdx.x; tile < ntiles; tile += gridDim.x) {
        const long row0 = (long)tile * 64;

        short8 aE[4];
#pragma unroll
        for (int ks = 0; ks < 4; ++ks)
            aE[ks] = *(const short8*)&emb[(row0 + w * 16 + i) * ED + ks * 32 + q * 8];
        float en[4];
#pragma unroll
        for (int r = 0; r < 4; ++r) en[r] = en2[row0 + w * 16 + q * 4 + r];

        floatx4 s1[4];
#pragma unroll
        for (int ct = 0; ct < 4; ++ct) s1[ct] = (floatx4){0.f, 0.f, 0.f, 0.f};
#pragma unroll
        for (int ks = 0; ks < 4; ++ks)
#pragma unroll
            for (int ct = 0; ct < 4; ++ct)
                s1[ct] = __builtin_amdgcn_mfma_f32_16x16x32_bf16(aE[ks], bP[ct][ks], s1[ct], 0, 0, 0);

#pragma unroll
        for (int r = 0; r < 4; ++r) {
            long row = row0 + w * 16 + q * 4 + r;
#pragma unroll
            for (int ct = 0; ct < 4; ++ct) {
                float d2 = en[r] + pn[ct] - 2.f * s1[ct][r];
                out[row * NC + ct * 16 + i] = -sqrtf(fmaxf(d2, 0.f));
            }
        }
    }
}

// ---------------------------------------------------------------------------
extern "C" void kernel_launch(void* const* d_in, const int* in_sizes, int n_in,
                              void* d_out, int out_size, void* d_ws, size_t ws_size,
                              hipStream_t stream)
{
    (void)in_sizes; (void)n_in; (void)out_size; (void)ws_size;

    const float* support = (const float*)d_in[0];
    const float* query   = (const float*)d_in[1];
    const int*   labels  = (const int*)d_in[2];
    const float* W       = (const float*)d_in[3];
    const float* bias    = (const float*)d_in[4];
    float* out = (float*)d_out;

    unsigned short* emb = (unsigned short*)d_ws;                 // [NTOT][128] bf16
    float* en2 = (float*)(emb + (size_t)NTOT * ED);              // [NTOT]
    unsigned short* WT = (unsigned short*)(en2 + NTOT);          // [128][512] bf16
    float* proto0 = (float*)(WT + 128 * 512);                    // [64][128]
    float* protoA = proto0 + NC * ED;
    float* protoB = protoA + NC * ED;
    float* part   = protoB + NC * ED;                            // [PGRID][64*128]

    prep_wt<<<64, 256, 0, stream>>>(W, WT);
    encode_mfma<<<(NS + 255) / 256, 512, 0, stream>>>(support, WT, bias, emb, en2, NS);
    encode_mfma<<<(NQ + 255) / 256, 512, 0, stream>>>(query, WT, bias,
                                                      emb + (size_t)NS * ED, en2 + NS, NQ);
    proto_init<<<NC, ED, 0, stream>>>(emb, labels, proto0);

    propagate<<<PGRID, 256, 0, stream>>>(emb, en2, proto0, 1.0f, part);
    reduce_partials<<<32, 256, 0, stream>>>(part, protoA);

    propagate<<<PGRID, 256, 0, stream>>>(emb, en2, protoA, INV_N, part);
    reduce_partials<<<32, 256, 0, stream>>>(part, protoB);

    propagate<<<PGRID, 256, 0, stream>>>(emb, en2, protoB, INV_N, part);
    reduce_partials<<<32, 256, 0, stream>>>(part, protoA);

    logits_k<<<1024, 256, 0, stream>>>(emb + (size_t)NS * ED, en2 + NS,
                                       protoA, INV_N, out);
}

// Round 4
// 972.365 us; speedup vs baseline: 1.0772x; 1.0772x over previous
//
#include <hip/hip_runtime.h>

#define NS 3200
#define NQ 200000
#define NTOT (NS + NQ)      // 203200 = 64 * 3175
#define KIN 512
#define ED 128
#define NC 64
#define INV_N (1.0f / (float)NTOT)
#define PGRID 512           // propagate grid; partial slabs sized to this

typedef short short8 __attribute__((ext_vector_type(8)));
typedef short short4v __attribute__((ext_vector_type(4)));
typedef float floatx4 __attribute__((ext_vector_type(4)));

static __device__ __forceinline__ unsigned short f2bf(float f) {
    unsigned int u = __float_as_uint(f);
    u += 0x7FFF + ((u >> 16) & 1);          // round-to-nearest-even
    return (unsigned short)(u >> 16);
}
static __device__ __forceinline__ float bf2f(unsigned short h) {
    return __uint_as_float(((unsigned int)h) << 16);
}

// ---------------------------------------------------------------------------
// One-time: WTbf[n][k] = bf16(W[k][n])   (128 x 512)
// ---------------------------------------------------------------------------
__global__ __launch_bounds__(256) void prep_wt(const float* __restrict__ W,
                                               unsigned short* __restrict__ WT)
{
    int idx = blockIdx.x * 256 + threadIdx.x;
#pragma unroll
    for (int p = 0; p < 4; ++p) {
        int id = idx + p * 16384;          // 64 blocks * 256 thr * 4 = 65536
        int n = id >> 9, k = id & 511;
        WT[n * 512 + k] = f2bf(W[k * 128 + n]);
    }
}

// ---------------------------------------------------------------------------
// Encoder v3: LDS-staged X (double-buffered, ONE barrier per K-step),
// W fragments direct from L2-resident WT (128 KB, no barrier dependency).
// BM=64 rows, 256 thr (4 waves), wave w owns rows w*16..+15 x all 128 cols.
// Per K-step (BK=64): issue next X loads -> barrier -> ds_read A + global W
// + 16 MFMA -> cvt+write next buffer. Staging overlaps compute; HBM-bound.
// ---------------------------------------------------------------------------
__global__ __launch_bounds__(256) void encode_mfma(
    const float* __restrict__ X, const unsigned short* __restrict__ WT,
    const float* __restrict__ bias, unsigned short* __restrict__ emb,
    float* __restrict__ en2)
{
    __shared__ unsigned short Xs[2][64 * 72];   // bf16 [row][k], stride 72

    const int t = threadIdx.x;
    const int w = t >> 6, lane = t & 63, q = lane >> 4, i = lane & 15;
    const long row0 = (long)blockIdx.x * 64;

    // staging map: thread t covers rows (t>>4)+p*16, cols (t&15)*4 (float4)
    const int sr = t >> 4;
    const int skf = t & 15;
    const float* xbase = &X[(row0 + sr) * KIN + skf * 4];

    floatx4 acc[8];
#pragma unroll
    for (int ct = 0; ct < 8; ++ct) acc[ct] = (floatx4){0.f, 0.f, 0.f, 0.f};

    float4 L[4];
#define STAGE_LOAD(S)                                                          \
    {                                                                          \
        _Pragma("unroll")                                                      \
        for (int p = 0; p < 4; ++p)                                            \
            L[p] = *(const float4*)&xbase[(long)p * 16 * KIN + (S) * 64];      \
    }
#define STAGE_WRITE(B)                                                         \
    {                                                                          \
        _Pragma("unroll")                                                      \
        for (int p = 0; p < 4; ++p) {                                          \
            short4v h;                                                         \
            h[0] = (short)f2bf(L[p].x); h[1] = (short)f2bf(L[p].y);            \
            h[2] = (short)f2bf(L[p].z); h[3] = (short)f2bf(L[p].w);            \
            *(short4v*)&Xs[B][(sr + p * 16) * 72 + skf * 4] = h;               \
        }                                                                      \
    }

    STAGE_LOAD(0)
    STAGE_WRITE(0)

#pragma unroll
    for (int s = 0; s < 8; ++s) {
        if (s < 7) STAGE_LOAD(s + 1)            // issue early (T14)
        __syncthreads();                        // buf[s&1] ready; prev reads done
        const unsigned short* xsb = &Xs[s & 1][0];
#pragma unroll
        for (int ks = 0; ks < 2; ++ks) {
            short8 a = *(const short8*)&xsb[(w * 16 + i) * 72 + ks * 32 + q * 8];
#pragma unroll
            for (int ct = 0; ct < 8; ++ct) {
                short8 b = *(const short8*)&WT[(ct * 16 + i) * 512 + s * 64 + ks * 32 + q * 8];
                acc[ct] = __builtin_amdgcn_mfma_f32_16x16x32_bf16(a, b, acc[ct], 0, 0, 0);
            }
        }
        if (s < 7) STAGE_WRITE((s + 1) & 1)     // write late, after compute
    }
#undef STAGE_LOAD
#undef STAGE_WRITE

    // epilogue: bias, store bf16, row norms
    float sq[4] = {0.f, 0.f, 0.f, 0.f};
#pragma unroll
    for (int ct = 0; ct < 8; ++ct) {
        float bb = bias[ct * 16 + i];
#pragma unroll
        for (int r = 0; r < 4; ++r) {
            float v = acc[ct][r] + bb;
            long row = row0 + w * 16 + q * 4 + r;
            emb[row * ED + ct * 16 + i] = f2bf(v);
            sq[r] += v * v;
        }
    }
#pragma unroll
    for (int r = 0; r < 4; ++r) {
        float s = sq[r];
        s += __shfl_xor(s, 1); s += __shfl_xor(s, 2);
        s += __shfl_xor(s, 4); s += __shfl_xor(s, 8);
        if (i == 0) en2[row0 + w * 16 + q * 4 + r] = s;
    }
}

// ---------------------------------------------------------------------------
// Initial prototypes: per-class mean of support embeddings.
// ---------------------------------------------------------------------------
__global__ __launch_bounds__(128) void proto_init(
    const unsigned short* __restrict__ emb, const int* __restrict__ labels,
    float* __restrict__ proto)
{
    const int c = blockIdx.x, d = threadIdx.x;
    float acc = 0.f; int cnt = 0;
    for (int r4 = 0; r4 < NS; r4 += 4) {
        int4 lb = *(const int4*)&labels[r4];
        if (lb.x == c) { acc += bf2f(emb[(r4 + 0) * ED + d]); cnt++; }
        if (lb.y == c) { acc += bf2f(emb[(r4 + 1) * ED + d]); cnt++; }
        if (lb.z == c) { acc += bf2f(emb[(r4 + 2) * ED + d]); cnt++; }
        if (lb.w == c) { acc += bf2f(emb[(r4 + 3) * ED + d]); cnt++; }
    }
    proto[c * ED + d] = acc / fmaxf((float)cnt, 1.0f);
}

// ---------------------------------------------------------------------------
// Fused propagation: S = E @ P^T (MFMA) -> softmax (regs) -> P' += A^T @ E (MFMA)
// 256 thr (4 waves), 64-row tiles, grid-stride; per-block partial slab instead
// of global atomics (deterministic, no L2 atomic serialization).
// ---------------------------------------------------------------------------
__global__ __launch_bounds__(256) void propagate(
    const unsigned short* __restrict__ emb, const float* __restrict__ en2,
    const float* __restrict__ proto_src, float scale,
    float* __restrict__ partial)
{
    __shared__ unsigned short Pbf[64 * 136];  // [class][d], stride 136
    __shared__ unsigned short ET[128 * 66];   // [d][row],   stride 66 (b16-write spread)
    __shared__ unsigned short ScT[64 * 72];   // [class][row], stride 72
    __shared__ float pn2s[64];

    const int t = threadIdx.x;
    const int w = t >> 6, lane = t & 63, q = lane >> 4, i = lane & 15;

    // prototype prep: scale, bf16, norms
    {
        int c = t >> 2, part = t & 3;
        const float* src = &proto_src[c * 128 + part * 32];
        float sqv = 0.f;
#pragma unroll 8
        for (int j = 0; j < 32; ++j) {
            float v = src[j] * scale;
            Pbf[c * 136 + part * 32 + j] = f2bf(v);
            sqv += v * v;
        }
        sqv += __shfl_xor(sqv, 1);
        sqv += __shfl_xor(sqv, 2);
        if (part == 0) pn2s[c] = sqv;
    }
    __syncthreads();

    // hoist B-fragments (prototypes) + pn to registers — constant over tiles
    short8 bP[4][4];
#pragma unroll
    for (int ct = 0; ct < 4; ++ct)
#pragma unroll
        for (int ks = 0; ks < 4; ++ks)
            bP[ct][ks] = *(const short8*)&Pbf[(ct * 16 + i) * 136 + ks * 32 + q * 8];
    float pn[4];
#pragma unroll
    for (int ct = 0; ct < 4; ++ct) pn[ct] = pn2s[ct * 16 + i];

    floatx4 acc2[8];
#pragma unroll
    for (int nt = 0; nt < 8; ++nt) acc2[nt] = (floatx4){0.f, 0.f, 0.f, 0.f};

    const int ntiles = NTOT / 64;
    for (int tile = blockIdx.x; tile < ntiles; tile += gridDim.x) {
        const long row0 = (long)tile * 64;

        // A-fragments straight from global bf16 emb (16B/lane)
        short8 aE[4];
#pragma unroll
        for (int ks = 0; ks < 4; ++ks)
            aE[ks] = *(const short8*)&emb[(row0 + w * 16 + i) * ED + ks * 32 + q * 8];
        float en[4];
#pragma unroll
        for (int r = 0; r < 4; ++r) en[r] = en2[row0 + w * 16 + q * 4 + r];

        // transpose E tile into LDS for GEMM2 B-operand
#pragma unroll
        for (int ks = 0; ks < 4; ++ks)
#pragma unroll
            for (int j = 0; j < 8; ++j)
                ET[(ks * 32 + q * 8 + j) * 66 + w * 16 + i] = (unsigned short)aE[ks][j];

        // GEMM1: S[16 rows x 64 classes]
        floatx4 s1[4];
#pragma unroll
        for (int ct = 0; ct < 4; ++ct) s1[ct] = (floatx4){0.f, 0.f, 0.f, 0.f};
#pragma unroll
        for (int ks = 0; ks < 4; ++ks)
#pragma unroll
            for (int ct = 0; ct < 4; ++ct)
                s1[ct] = __builtin_amdgcn_mfma_f32_16x16x32_bf16(aE[ks], bP[ct][ks], s1[ct], 0, 0, 0);

        // softmax over 64 classes (4 cts in regs x 16 lanes of quad)
        float attn[4][4];   // [ct][r]
#pragma unroll
        for (int r = 0; r < 4; ++r) {
            float sc[4];
#pragma unroll
            for (int ct = 0; ct < 4; ++ct) {
                float d2 = en[r] + pn[ct] - 2.f * s1[ct][r];
                sc[ct] = -sqrtf(fmaxf(d2, 0.f));
            }
            float mx = fmaxf(fmaxf(sc[0], sc[1]), fmaxf(sc[2], sc[3]));
            mx = fmaxf(mx, __shfl_xor(mx, 1));
            mx = fmaxf(mx, __shfl_xor(mx, 2));
            mx = fmaxf(mx, __shfl_xor(mx, 4));
            mx = fmaxf(mx, __shfl_xor(mx, 8));
            float sm = 0.f;
#pragma unroll
            for (int ct = 0; ct < 4; ++ct) { attn[ct][r] = __expf(sc[ct] - mx); sm += attn[ct][r]; }
            sm += __shfl_xor(sm, 1);
            sm += __shfl_xor(sm, 2);
            sm += __shfl_xor(sm, 4);
            sm += __shfl_xor(sm, 8);
            float inv = 1.f / sm;
#pragma unroll
            for (int ct = 0; ct < 4; ++ct) attn[ct][r] *= inv;
        }
        // write attn transposed: ScT[class][row] (4 rows packed per b64 write)
#pragma unroll
        for (int ct = 0; ct < 4; ++ct) {
            short4v pk;
            pk[0] = (short)f2bf(attn[ct][0]); pk[1] = (short)f2bf(attn[ct][1]);
            pk[2] = (short)f2bf(attn[ct][2]); pk[3] = (short)f2bf(attn[ct][3]);
            *(short4v*)&ScT[(ct * 16 + i) * 72 + w * 16 + q * 4] = pk;
        }
        __syncthreads();

        // GEMM2: wave w -> classes w*16..+15, all 128 dims, K = 64 rows
#pragma unroll
        for (int ks2 = 0; ks2 < 2; ++ks2) {
            short8 a2 = *(const short8*)&ScT[(w * 16 + i) * 72 + ks2 * 32 + q * 8];
#pragma unroll
            for (int nt = 0; nt < 8; ++nt) {
                union { short8 s; unsigned int u[4]; } b2;
                const unsigned short* base = &ET[(nt * 16 + i) * 66 + ks2 * 32 + q * 8];
                b2.u[0] = *(const unsigned int*)&base[0];
                b2.u[1] = *(const unsigned int*)&base[2];
                b2.u[2] = *(const unsigned int*)&base[4];
                b2.u[3] = *(const unsigned int*)&base[6];
                acc2[nt] = __builtin_amdgcn_mfma_f32_16x16x32_bf16(a2, b2.s, acc2[nt], 0, 0, 0);
            }
        }
        __syncthreads();
    }

    // per-block partial slab (replaces 4.2M global atomics)
    float* myp = partial + (size_t)blockIdx.x * (NC * ED);
#pragma unroll
    for (int nt = 0; nt < 8; ++nt)
#pragma unroll
        for (int r = 0; r < 4; ++r)
            myp[(w * 16 + q * 4 + r) * ED + nt * 16 + i] = acc2[nt][r];
}

// ---------------------------------------------------------------------------
// Sum the PGRID partial slabs -> proto sums (64x128)
// ---------------------------------------------------------------------------
__global__ __launch_bounds__(256) void reduce_partials(
    const float* __restrict__ partial, float* __restrict__ proto)
{
    int idx = blockIdx.x * 256 + threadIdx.x;   // grid 32 -> 8192 outputs
    float s = 0.f;
#pragma unroll 8
    for (int b = 0; b < PGRID; ++b) s += partial[(size_t)b * (NC * ED) + idx];
    proto[idx] = s;
}

// ---------------------------------------------------------------------------
// Final logits: out[q][c] = -sqrt(max(||e||^2 + ||p||^2 - 2 e.p, 0))
// ---------------------------------------------------------------------------
__global__ __launch_bounds__(256) void logits_k(
    const unsigned short* __restrict__ emb, const float* __restrict__ en2,
    const float* __restrict__ proto_src, float scale, float* __restrict__ out)
{
    __shared__ unsigned short Pbf[64 * 136];
    __shared__ float pn2s[64];

    const int t = threadIdx.x;
    const int w = t >> 6, lane = t & 63, q = lane >> 4, i = lane & 15;

    {
        int c = t >> 2, part = t & 3;
        const float* src = &proto_src[c * 128 + part * 32];
        float sqv = 0.f;
#pragma unroll 8
        for (int j = 0; j < 32; ++j) {
            float v = src[j] * scale;
            Pbf[c * 136 + part * 32 + j] = f2bf(v);
            sqv += v * v;
        }
        sqv += __shfl_xor(sqv, 1);
        sqv += __shfl_xor(sqv, 2);
        if (part == 0) pn2s[c] = sqv;
    }
    __syncthreads();

    short8 bP[4][4];
#pragma unroll
    for (int ct = 0; ct < 4; ++ct)
#pragma unroll
        for (int ks = 0; ks < 4; ++ks)
            bP[ct][ks] = *(const short8*)&Pbf[(ct * 16 + i) * 136 + ks * 32 + q * 8];
    float pn[4];
#pragma unroll
    for (int ct = 0; ct < 4; ++ct) pn[ct] = pn2s[ct * 16 + i];

    const int ntiles = NQ / 64;
    for (int tile = blockIdx.x; tile < ntiles; tile += gridDim.x) {
        const long row0 = (long)tile * 64;

        short8 aE[4];
#pragma unroll
        for (int ks = 0; ks < 4; ++ks)
            aE[ks] = *(const short8*)&emb[(row0 + w * 16 + i) * ED + ks * 32 + q * 8];
        float en[4];
#pragma unroll
        for (int r = 0; r < 4; ++r) en[r] = en2[row0 + w * 16 + q * 4 + r];

        floatx4 s1[4];
#pragma unroll
        for (int ct = 0; ct < 4; ++ct) s1[ct] = (floatx4){0.f, 0.f, 0.f, 0.f};
#pragma unroll
        for (int ks = 0; ks < 4; ++ks)
#pragma unroll
            for (int ct = 0; ct < 4; ++ct)
                s1[ct] = __builtin_amdgcn_mfma_f32_16x16x32_bf16(aE[ks], bP[ct][ks], s1[ct], 0, 0, 0);

#pragma unroll
        for (int r = 0; r < 4; ++r) {
            long row = row0 + w * 16 + q * 4 + r;
#pragma unroll
            for (int ct = 0; ct < 4; ++ct) {
                float d2 = en[r] + pn[ct] - 2.f * s1[ct][r];
                out[row * NC + ct * 16 + i] = -sqrtf(fmaxf(d2, 0.f));
            }
        }
    }
}

// ---------------------------------------------------------------------------
extern "C" void kernel_launch(void* const* d_in, const int* in_sizes, int n_in,
                              void* d_out, int out_size, void* d_ws, size_t ws_size,
                              hipStream_t stream)
{
    (void)in_sizes; (void)n_in; (void)out_size; (void)ws_size;

    const float* support = (const float*)d_in[0];
    const float* query   = (const float*)d_in[1];
    const int*   labels  = (const int*)d_in[2];
    const float* W       = (const float*)d_in[3];
    const float* bias    = (const float*)d_in[4];
    float* out = (float*)d_out;

    unsigned short* emb = (unsigned short*)d_ws;                 // [NTOT][128] bf16
    float* en2 = (float*)(emb + (size_t)NTOT * ED);              // [NTOT]
    unsigned short* WT = (unsigned short*)(en2 + NTOT);          // [128][512] bf16
    float* proto0 = (float*)(WT + 128 * 512);                    // [64][128]
    float* protoA = proto0 + NC * ED;
    float* protoB = protoA + NC * ED;
    float* part   = protoB + NC * ED;                            // [PGRID][64*128]

    prep_wt<<<64, 256, 0, stream>>>(W, WT);
    encode_mfma<<<NS / 64, 256, 0, stream>>>(support, WT, bias, emb, en2);
    encode_mfma<<<NQ / 64, 256, 0, stream>>>(query, WT, bias,
                                             emb + (size_t)NS * ED, en2 + NS);
    proto_init<<<NC, ED, 0, stream>>>(emb, labels, proto0);

    propagate<<<PGRID, 256, 0, stream>>>(emb, en2, proto0, 1.0f, part);
    reduce_partials<<<32, 256, 0, stream>>>(part, protoA);

    propagate<<<PGRID, 256, 0, stream>>>(emb, en2, protoA, INV_N, part);
    reduce_partials<<<32, 256, 0, stream>>>(part, protoB);

    propagate<<<PGRID, 256, 0, stream>>>(emb, en2, protoB, INV_N, part);
    reduce_partials<<<32, 256, 0, stream>>>(part, protoA);

    logits_k<<<1024, 256, 0, stream>>>(emb + (size_t)NS * ED, en2 + NS,
                                       protoA, INV_N, out);
}

// Round 5
// 963.296 us; speedup vs baseline: 1.0874x; 1.0094x over previous
//
#include <hip/hip_runtime.h>

#define NS 3200
#define NQ 200000
#define NTOT (NS + NQ)      // 203200 = 64 * 3175
#define KIN 512
#define ED 128
#define NC 64
#define INV_N (1.0f / (float)NTOT)
#define PGRID 1536          // propagate grid; 6 blocks/CU resident

typedef short short8 __attribute__((ext_vector_type(8)));
typedef short short4v __attribute__((ext_vector_type(4)));
typedef float floatx4 __attribute__((ext_vector_type(4)));

static __device__ __forceinline__ unsigned short f2bf(float f) {
    unsigned int u = __float_as_uint(f);
    u += 0x7FFF + ((u >> 16) & 1);          // round-to-nearest-even
    return (unsigned short)(u >> 16);
}
static __device__ __forceinline__ float bf2f(unsigned short h) {
    return __uint_as_float(((unsigned int)h) << 16);
}

// async global->LDS, 16B per lane; lds dest = wave-uniform base + lane*16
static __device__ __forceinline__ void gload_lds16(const float* g, float* l) {
    __builtin_amdgcn_global_load_lds(
        (const __attribute__((address_space(1))) void*)g,
        (__attribute__((address_space(3))) void*)l, 16, 0, 0);
}

// ---------------------------------------------------------------------------
// One-time: WTbf[n][k] = bf16(W[k][n])   (128 x 512)
// ---------------------------------------------------------------------------
__global__ __launch_bounds__(256) void prep_wt(const float* __restrict__ W,
                                               unsigned short* __restrict__ WT)
{
    int idx = blockIdx.x * 256 + threadIdx.x;
#pragma unroll
    for (int p = 0; p < 4; ++p) {
        int id = idx + p * 16384;          // 64 blocks * 256 thr * 4 = 65536
        int n = id >> 9, k = id & 511;
        WT[n * 512 + k] = f2bf(W[k * 128 + n]);
    }
}

// ---------------------------------------------------------------------------
// Encoder v4: global_load_lds fp32 staging (async, no VGPR round-trip),
// XOR-swizzled LDS (pre-swizzled SOURCE + swizzled READ — both sides),
// batched WT b-frag loads. 256 thr / 4 waves / BM=64 / BK=64 / 8 K-steps.
// LDS 32 KB -> 5 blocks/CU; loads stay in flight across the compute phase.
// ---------------------------------------------------------------------------
__global__ __launch_bounds__(256) void encode_mfma(
    const float* __restrict__ X, const unsigned short* __restrict__ WT,
    const float* __restrict__ bias, unsigned short* __restrict__ emb,
    float* __restrict__ en2)
{
    __shared__ float Xs[2][64 * 64];    // fp32 [row][kf], linear; swizzle in content

    const int t = threadIdx.x;
    const int w = t >> 6, lane = t & 63, q = lane >> 4, i = lane & 15;
    const long row0 = (long)blockIdx.x * 64;

    const int srow = lane >> 4;         // row within 4-row group
    const int c4   = lane & 15;         // float4 chunk within row

    floatx4 acc[8];
#pragma unroll
    for (int ct = 0; ct < 8; ++ct) acc[ct] = (floatx4){0.f, 0.f, 0.f, 0.f};

    // stage K-step S into buffer B: 16 wave-instrs (4/wave), 1KB each.
    // LDS[r*64 + u] holds X[row0+r][S*64 + (u ^ ((r&7)<<2))]  (content swizzle)
#define STAGE(B, S)                                                            \
    {                                                                          \
        _Pragma("unroll")                                                      \
        for (int p = 0; p < 4; ++p) {                                          \
            int ii = w * 4 + p;                                                \
            int r  = ii * 4 + srow;                                            \
            int sw = (r & 7) << 2;                                             \
            const float* g = &X[(row0 + r) * KIN + (S) * 64 + ((c4 * 4) ^ sw)];\
            gload_lds16(g, &Xs[B][ii * 256]);                                  \
        }                                                                      \
    }

    STAGE(0, 0)

    for (int s = 0; s < 8; ++s) {
        __syncthreads();                 // buf[s&1] landed (barrier drains vmcnt)
        if (s < 7) STAGE((s + 1) & 1, s + 1)   // async prefetch next K-step

        // batch all 16 B-fragments -> one load burst (L2-resident WT)
        short8 bfr[2][8];
#pragma unroll
        for (int ks = 0; ks < 2; ++ks)
#pragma unroll
            for (int ct = 0; ct < 8; ++ct)
                bfr[ks][ct] = *(const short8*)&WT[(ct * 16 + i) * 512 + s * 64 + ks * 32 + q * 8];

        const float* xb = &Xs[s & 1][(w * 16 + i) * 64];
        const int swr = (i & 7) << 2;    // (w*16+i)&7 == i&7
#pragma unroll
        for (int ks = 0; ks < 2; ++ks) {
            int c0 = ks * 32 + q * 8;
            floatx4 fa = *(const floatx4*)&xb[c0 ^ swr];
            floatx4 fb = *(const floatx4*)&xb[(c0 + 4) ^ swr];
            short8 a;
            a[0] = (short)f2bf(fa[0]); a[1] = (short)f2bf(fa[1]);
            a[2] = (short)f2bf(fa[2]); a[3] = (short)f2bf(fa[3]);
            a[4] = (short)f2bf(fb[0]); a[5] = (short)f2bf(fb[1]);
            a[6] = (short)f2bf(fb[2]); a[7] = (short)f2bf(fb[3]);
#pragma unroll
            for (int ct = 0; ct < 8; ++ct)
                acc[ct] = __builtin_amdgcn_mfma_f32_16x16x32_bf16(a, bfr[ks][ct], acc[ct], 0, 0, 0);
        }
    }
#undef STAGE

    // epilogue: bias, store bf16, row norms
    float sq[4] = {0.f, 0.f, 0.f, 0.f};
#pragma unroll
    for (int ct = 0; ct < 8; ++ct) {
        float bb = bias[ct * 16 + i];
#pragma unroll
        for (int r = 0; r < 4; ++r) {
            float v = acc[ct][r] + bb;
            long row = row0 + w * 16 + q * 4 + r;
            emb[row * ED + ct * 16 + i] = f2bf(v);
            sq[r] += v * v;
        }
    }
#pragma unroll
    for (int r = 0; r < 4; ++r) {
        float s = sq[r];
        s += __shfl_xor(s, 1); s += __shfl_xor(s, 2);
        s += __shfl_xor(s, 4); s += __shfl_xor(s, 8);
        if (i == 0) en2[row0 + w * 16 + q * 4 + r] = s;
    }
}

// ---------------------------------------------------------------------------
// Initial prototypes: per-class mean of support embeddings.
// ---------------------------------------------------------------------------
__global__ __launch_bounds__(128) void proto_init(
    const unsigned short* __restrict__ emb, const int* __restrict__ labels,
    float* __restrict__ proto)
{
    const int c = blockIdx.x, d = threadIdx.x;
    float acc = 0.f; int cnt = 0;
    for (int r4 = 0; r4 < NS; r4 += 4) {
        int4 lb = *(const int4*)&labels[r4];
        if (lb.x == c) { acc += bf2f(emb[(r4 + 0) * ED + d]); cnt++; }
        if (lb.y == c) { acc += bf2f(emb[(r4 + 1) * ED + d]); cnt++; }
        if (lb.z == c) { acc += bf2f(emb[(r4 + 2) * ED + d]); cnt++; }
        if (lb.w == c) { acc += bf2f(emb[(r4 + 3) * ED + d]); cnt++; }
    }
    proto[c * ED + d] = acc / fmaxf((float)cnt, 1.0f);
}

// ---------------------------------------------------------------------------
// Fused propagation. LDS trimmed via union (Pbf dead after reg-hoist) ->
// 26.4 KB -> 6 blocks/CU; grid 1536 for latency hiding.
// ---------------------------------------------------------------------------
__global__ __launch_bounds__(256) void propagate(
    const unsigned short* __restrict__ emb, const float* __restrict__ en2,
    const float* __restrict__ proto_src, float scale,
    float* __restrict__ partial)
{
    __shared__ union {
        unsigned short Pbf[64 * 136];               // prologue only
        struct {
            unsigned short ET[128 * 66];            // [d][row]
            unsigned short ScT[64 * 72];            // [class][row]
        } m;
    } sh;
    __shared__ float pn2s[64];

    const int t = threadIdx.x;
    const int w = t >> 6, lane = t & 63, q = lane >> 4, i = lane & 15;

    // prototype prep: scale, bf16, norms
    {
        int c = t >> 2, part = t & 3;
        const float* src = &proto_src[c * 128 + part * 32];
        float sqv = 0.f;
#pragma unroll 8
        for (int j = 0; j < 32; ++j) {
            float v = src[j] * scale;
            sh.Pbf[c * 136 + part * 32 + j] = f2bf(v);
            sqv += v * v;
        }
        sqv += __shfl_xor(sqv, 1);
        sqv += __shfl_xor(sqv, 2);
        if (part == 0) pn2s[c] = sqv;
    }
    __syncthreads();

    // hoist B-fragments (prototypes) + pn to registers — constant over tiles
    short8 bP[4][4];
#pragma unroll
    for (int ct = 0; ct < 4; ++ct)
#pragma unroll
        for (int ks = 0; ks < 4; ++ks)
            bP[ct][ks] = *(const short8*)&sh.Pbf[(ct * 16 + i) * 136 + ks * 32 + q * 8];
    float pn[4];
#pragma unroll
    for (int ct = 0; ct < 4; ++ct) pn[ct] = pn2s[ct * 16 + i];
    __syncthreads();               // Pbf reads done before ET/ScT overwrite

    floatx4 acc2[8];
#pragma unroll
    for (int nt = 0; nt < 8; ++nt) acc2[nt] = (floatx4){0.f, 0.f, 0.f, 0.f};

    const int ntiles = NTOT / 64;
    for (int tile = blockIdx.x; tile < ntiles; tile += gridDim.x) {
        const long row0 = (long)tile * 64;

        // A-fragments straight from global bf16 emb (16B/lane)
        short8 aE[4];
#pragma unroll
        for (int ks = 0; ks < 4; ++ks)
            aE[ks] = *(const short8*)&emb[(row0 + w * 16 + i) * ED + ks * 32 + q * 8];
        float en[4];
#pragma unroll
        for (int r = 0; r < 4; ++r) en[r] = en2[row0 + w * 16 + q * 4 + r];

        // transpose E tile into LDS for GEMM2 B-operand
#pragma unroll
        for (int ks = 0; ks < 4; ++ks)
#pragma unroll
            for (int j = 0; j < 8; ++j)
                sh.m.ET[(ks * 32 + q * 8 + j) * 66 + w * 16 + i] = (unsigned short)aE[ks][j];

        // GEMM1: S[16 rows x 64 classes]
        floatx4 s1[4];
#pragma unroll
        for (int ct = 0; ct < 4; ++ct) s1[ct] = (floatx4){0.f, 0.f, 0.f, 0.f};
#pragma unroll
        for (int ks = 0; ks < 4; ++ks)
#pragma unroll
            for (int ct = 0; ct < 4; ++ct)
                s1[ct] = __builtin_amdgcn_mfma_f32_16x16x32_bf16(aE[ks], bP[ct][ks], s1[ct], 0, 0, 0);

        // softmax over 64 classes (4 cts in regs x 16 lanes of quad)
        float attn[4][4];   // [ct][r]
#pragma unroll
        for (int r = 0; r < 4; ++r) {
            float sc[4];
#pragma unroll
            for (int ct = 0; ct < 4; ++ct) {
                float d2 = en[r] + pn[ct] - 2.f * s1[ct][r];
                sc[ct] = -sqrtf(fmaxf(d2, 0.f));
            }
            float mx = fmaxf(fmaxf(sc[0], sc[1]), fmaxf(sc[2], sc[3]));
            mx = fmaxf(mx, __shfl_xor(mx, 1));
            mx = fmaxf(mx, __shfl_xor(mx, 2));
            mx = fmaxf(mx, __shfl_xor(mx, 4));
            mx = fmaxf(mx, __shfl_xor(mx, 8));
            float sm = 0.f;
#pragma unroll
            for (int ct = 0; ct < 4; ++ct) { attn[ct][r] = __expf(sc[ct] - mx); sm += attn[ct][r]; }
            sm += __shfl_xor(sm, 1);
            sm += __shfl_xor(sm, 2);
            sm += __shfl_xor(sm, 4);
            sm += __shfl_xor(sm, 8);
            float inv = 1.f / sm;
#pragma unroll
            for (int ct = 0; ct < 4; ++ct) attn[ct][r] *= inv;
        }
        // write attn transposed: ScT[class][row] (4 rows packed per b64 write)
#pragma unroll
        for (int ct = 0; ct < 4; ++ct) {
            short4v pk;
            pk[0] = (short)f2bf(attn[ct][0]); pk[1] = (short)f2bf(attn[ct][1]);
            pk[2] = (short)f2bf(attn[ct][2]); pk[3] = (short)f2bf(attn[ct][3]);
            *(short4v*)&sh.m.ScT[(ct * 16 + i) * 72 + w * 16 + q * 4] = pk;
        }
        __syncthreads();

        // GEMM2: wave w -> classes w*16..+15, all 128 dims, K = 64 rows
#pragma unroll
        for (int ks2 = 0; ks2 < 2; ++ks2) {
            short8 a2 = *(const short8*)&sh.m.ScT[(w * 16 + i) * 72 + ks2 * 32 + q * 8];
#pragma unroll
            for (int nt = 0; nt < 8; ++nt) {
                union { short8 s; unsigned int u[4]; } b2;
                const unsigned short* base = &sh.m.ET[(nt * 16 + i) * 66 + ks2 * 32 + q * 8];
                b2.u[0] = *(const unsigned int*)&base[0];
                b2.u[1] = *(const unsigned int*)&base[2];
                b2.u[2] = *(const unsigned int*)&base[4];
                b2.u[3] = *(const unsigned int*)&base[6];
                acc2[nt] = __builtin_amdgcn_mfma_f32_16x16x32_bf16(a2, b2.s, acc2[nt], 0, 0, 0);
            }
        }
        __syncthreads();
    }

    // per-block partial slab
    float* myp = partial + (size_t)blockIdx.x * (NC * ED);
#pragma unroll
    for (int nt = 0; nt < 8; ++nt)
#pragma unroll
        for (int r = 0; r < 4; ++r)
            myp[(w * 16 + q * 4 + r) * ED + nt * 16 + i] = acc2[nt][r];
}

// ---------------------------------------------------------------------------
// Sum PGRID partial slabs -> proto sums (64x128). 2-level: 8 part-sums in
// parallel per output, LDS reduce. Grid 256 x 256 thr, no atomics.
// ---------------------------------------------------------------------------
__global__ __launch_bounds__(256) void reduce_partials(
    const float* __restrict__ partial, float* __restrict__ proto)
{
    __shared__ float red[256];
    const int t = threadIdx.x;
    const int o = blockIdx.x * 32 + (t & 31);   // output idx (8192 total)
    const int p = t >> 5;                       // part 0..7, 192 slabs each
    float s = 0.f;
    const float* base = partial + (size_t)(p * (PGRID / 8)) * (NC * ED) + o;
#pragma unroll 4
    for (int b = 0; b < PGRID / 8; ++b) s += base[(size_t)b * (NC * ED)];
    red[t] = s;
    __syncthreads();
    if (t < 32) {
        float r = red[t];
#pragma unroll
        for (int pp = 1; pp < 8; ++pp) r += red[pp * 32 + t];
        proto[o] = r;
    }
}

// ---------------------------------------------------------------------------
// Final logits: out[q][c] = -sqrt(max(||e||^2 + ||p||^2 - 2 e.p, 0))
// ---------------------------------------------------------------------------
__global__ __launch_bounds__(256) void logits_k(
    const unsigned short* __restrict__ emb, const float* __restrict__ en2,
    const float* __restrict__ proto_src, float scale, float* __restrict__ out)
{
    __shared__ unsigned short Pbf[64 * 136];
    __shared__ float pn2s[64];

    const int t = threadIdx.x;
    const int w = t >> 6, lane = t & 63, q = lane >> 4, i = lane & 15;

    {
        int c = t >> 2, part = t & 3;
        const float* src = &proto_src[c * 128 + part * 32];
        float sqv = 0.f;
#pragma unroll 8
        for (int j = 0; j < 32; ++j) {
            float v = src[j] * scale;
            Pbf[c * 136 + part * 32 + j] = f2bf(v);
            sqv += v * v;
        }
        sqv += __shfl_xor(sqv, 1);
        sqv += __shfl_xor(sqv, 2);
        if (part == 0) pn2s[c] = sqv;
    }
    __syncthreads();

    short8 bP[4][4];
#pragma unroll
    for (int ct = 0; ct < 4; ++ct)
#pragma unroll
        for (int ks = 0; ks < 4; ++ks)
            bP[ct][ks] = *(const short8*)&Pbf[(ct * 16 + i) * 136 + ks * 32 + q * 8];
    float pn[4];
#pragma unroll
    for (int ct = 0; ct < 4; ++ct) pn[ct] = pn2s[ct * 16 + i];

    const int ntiles = NQ / 64;
    for (int tile = blockIdx.x; tile < ntiles; tile += gridDim.x) {
        const long row0 = (long)tile * 64;

        short8 aE[4];
#pragma unroll
        for (int ks = 0; ks < 4; ++ks)
            aE[ks] = *(const short8*)&emb[(row0 + w * 16 + i) * ED + ks * 32 + q * 8];
        float en[4];
#pragma unroll
        for (int r = 0; r < 4; ++r) en[r] = en2[row0 + w * 16 + q * 4 + r];

        floatx4 s1[4];
#pragma unroll
        for (int ct = 0; ct < 4; ++ct) s1[ct] = (floatx4){0.f, 0.f, 0.f, 0.f};
#pragma unroll
        for (int ks = 0; ks < 4; ++ks)
#pragma unroll
            for (int ct = 0; ct < 4; ++ct)
                s1[ct] = __builtin_amdgcn_mfma_f32_16x16x32_bf16(aE[ks], bP[ct][ks], s1[ct], 0, 0, 0);

#pragma unroll
        for (int r = 0; r < 4; ++r) {
            long row = row0 + w * 16 + q * 4 + r;
#pragma unroll
            for (int ct = 0; ct < 4; ++ct) {
                float d2 = en[r] + pn[ct] - 2.f * s1[ct][r];
                out[row * NC + ct * 16 + i] = -sqrtf(fmaxf(d2, 0.f));
            }
        }
    }
}

// ---------------------------------------------------------------------------
extern "C" void kernel_launch(void* const* d_in, const int* in_sizes, int n_in,
                              void* d_out, int out_size, void* d_ws, size_t ws_size,
                              hipStream_t stream)
{
    (void)in_sizes; (void)n_in; (void)out_size; (void)ws_size;

    const float* support = (const float*)d_in[0];
    const float* query   = (const float*)d_in[1];
    const int*   labels  = (const int*)d_in[2];
    const float* W       = (const float*)d_in[3];
    const float* bias    = (const float*)d_in[4];
    float* out = (float*)d_out;

    unsigned short* emb = (unsigned short*)d_ws;                 // [NTOT][128] bf16
    float* en2 = (float*)(emb + (size_t)NTOT * ED);              // [NTOT]
    unsigned short* WT = (unsigned short*)(en2 + NTOT);          // [128][512] bf16
    float* proto0 = (float*)(WT + 128 * 512);                    // [64][128]
    float* protoA = proto0 + NC * ED;
    float* protoB = protoA + NC * ED;
    float* part   = protoB + NC * ED;                            // [PGRID][64*128]

    prep_wt<<<64, 256, 0, stream>>>(W, WT);
    encode_mfma<<<NS / 64, 256, 0, stream>>>(support, WT, bias, emb, en2);
    encode_mfma<<<NQ / 64, 256, 0, stream>>>(query, WT, bias,
                                             emb + (size_t)NS * ED, en2 + NS);
    proto_init<<<NC, ED, 0, stream>>>(emb, labels, proto0);

    propagate<<<PGRID, 256, 0, stream>>>(emb, en2, proto0, 1.0f, part);
    reduce_partials<<<256, 256, 0, stream>>>(part, protoA);

    propagate<<<PGRID, 256, 0, stream>>>(emb, en2, protoA, INV_N, part);
    reduce_partials<<<256, 256, 0, stream>>>(part, protoB);

    propagate<<<PGRID, 256, 0, stream>>>(emb, en2, protoB, INV_N, part);
    reduce_partials<<<256, 256, 0, stream>>>(part, protoA);

    logits_k<<<2048, 256, 0, stream>>>(emb + (size_t)NS * ED, en2 + NS,
                                       protoA, INV_N, out);
}